// Round 22
// baseline (113.753 us; speedup 1.0000x reference)
//
#include <hip/hip_runtime.h>
#include <hip/hip_bf16.h>

typedef __attribute__((ext_vector_type(8))) short short8;
typedef __attribute__((ext_vector_type(4))) float f32x4;

#define IN_F 512
#define OUT_F 512
#define BK 64
#define PHI_STEPS 64
#define NSTEPS 72
#define PAN 64                           // A image panel = 64 rows
#define ACH 512                          // A chunks per (panel, step)
#define BCH2 2048                        // B chunks per (nt256, step) (both layouts)
#define NT2 2
#define PART_ELEMS (8192 * OUT_F)
#define C2 (-10.2591705f)                // -(8/3)^2 * log2(e)

// Branchless RNE f32->bf16 (finite values only)
__device__ __forceinline__ short f2bf(float f) {
  unsigned u = __builtin_bit_cast(unsigned, f);
  u += 0x7fffu + ((u >> 16) & 1u);
  return (short)(u >> 16);
}
__device__ __forceinline__ float b2f(unsigned short u) {
  return __builtin_bit_cast(float, (unsigned)u << 16);
}

__device__ __forceinline__ void glds16(const void* g, void* l) {
  // 16B global->LDS; LDS base wave-uniform (HW adds lane*16); global src per-lane.
  __builtin_amdgcn_global_load_lds(
      (const __attribute__((address_space(1))) unsigned int*)g,
      (__attribute__((address_space(3))) unsigned int*)l, 16, 0, 0);
}

__device__ __forceinline__ float bsrc(const float* __restrict__ w,
                                      const float* __restrict__ sb,
                                      int k, int col) {
  return (k < IN_F * 8) ? w[(size_t)k * OUT_F + col]
                        : sb[(size_t)(k - IN_F * 8) * OUT_F + col];
}

// ---- B frag-image (for B-direct GEMM): per (nt,kt), chunk ci = (c*2+kk)*64+lane,
//      c = wn*4+fj (0..15); element j -> B[k=kt*64+(kk*4+(lane>>4))*8+j]
//                                        [nt*256 + c*16 + (lane&15)].
__global__ void __launch_bounds__(256) prep_bf(const float* __restrict__ w,
                                               const float* __restrict__ sb,
                                               short* __restrict__ img) {
  const int D = blockIdx.x * 256 + threadIdx.x;
  const int ci = D & (BCH2 - 1);
  const int im = D >> 11;
  const int s = im % NSTEPS;
  const int nt = im / NSTEPS;
  const int lane = ci & 63;
  const int kk = (ci >> 6) & 1;
  const int c = ci >> 7;                 // 0..15
  const int col = nt * 256 + c * 16 + (lane & 15);
  const int kbase = s * 64 + (kk * 4 + (lane >> 4)) * 8;
  short8 v;
#pragma unroll
  for (int j = 0; j < 8; ++j) v[j] = f2bf(bsrc(w, sb, kbase + j, col));
  *(short8*)&img[(size_t)D * 8] = v;
}

// ---- old-layout B images (mid fallback): chunk ci=n*8+slot, slot=oct^(n&7)
__global__ void __launch_bounds__(256) prep_b2(const float* __restrict__ w,
                                               const float* __restrict__ sb,
                                               short* __restrict__ img) {
  const int D = blockIdx.x * 256 + threadIdx.x;
  const int ci = D & (BCH2 - 1);
  const int im = D >> 11;
  const int s = im % NSTEPS;
  const int nt = im / NSTEPS;
  const int n = ci >> 3, slot = ci & 7;
  const int oct = slot ^ (n & 7);
  const int col = nt * 256 + n;
  short8 v;
#pragma unroll
  for (int j = 0; j < 8; ++j) v[j] = f2bf(bsrc(w, sb, s * 64 + oct * 8 + j, col));
  *(short8*)&img[(size_t)D * 8] = v;
}

// ---- A images: per (panel,s), chunk ci=m*8+slot, slot=oct^(m&7);
//      element j -> phi[panel*64+m][k=s*64+oct*8+j].
__global__ void __launch_bounds__(256) prep_a(const float* __restrict__ x,
                                              const float* __restrict__ rw,
                                              const float* __restrict__ rc,
                                              short* __restrict__ aimg) {
  const int D = blockIdx.x * 256 + threadIdx.x;
  const int ci = D & (ACH - 1);
  const int rest = D >> 9;
  const int s = rest % NSTEPS;
  const int pan = rest / NSTEPS;
  const int m = ci >> 3, slot = ci & 7;
  const int oct = slot ^ (m & 7);
  const int row = pan * PAN + m;
  short8 v;
  if (s < PHI_STEPS) {
    const int feat = s * 8 + oct;
    const float xv = x[(size_t)row * IN_F + feat];
    const float4 r0 = *(const float4*)(rw + feat * 8);
    const float4 r1 = *(const float4*)(rw + feat * 8 + 4);
    const float4 q0 = *(const float4*)(rc + feat * 8);
    const float4 q1 = *(const float4*)(rc + feat * 8 + 4);
    const float rwv[8] = {r0.x, r0.y, r0.z, r0.w, r1.x, r1.y, r1.z, r1.w};
    const float rcv[8] = {q0.x, q0.y, q0.z, q0.w, q1.x, q1.y, q1.z, q1.w};
#pragma unroll
    for (int j = 0; j < 8; ++j) {
      const float z = fmaf(xv, rwv[j], -rcv[j]);
      v[j] = f2bf(exp2f(C2 * z * z));
    }
  } else {
    const float* xp = x + (size_t)row * IN_F + (s - PHI_STEPS) * 64 + oct * 8;
    const float4 u0 = *(const float4*)xp, u1 = *(const float4*)(xp + 4);
    v[0] = f2bf(__cosf(u0.x)); v[1] = f2bf(__cosf(u0.y));
    v[2] = f2bf(__cosf(u0.z)); v[3] = f2bf(__cosf(u0.w));
    v[4] = f2bf(__cosf(u1.x)); v[5] = f2bf(__cosf(u1.y));
    v[6] = f2bf(__cosf(u1.z)); v[7] = f2bf(__cosf(u1.w));
  }
  *(short8*)&aimg[(size_t)D * 8] = v;
}

// out += bf16 partials p0+p1+p2
__global__ void __launch_bounds__(256) reduce3b(const short* __restrict__ part,
                                                float* __restrict__ out) {
  typedef __attribute__((ext_vector_type(4))) short short4v;
  const int n4 = PART_ELEMS / 4;
  const short4v* p0 = (const short4v*)part;
  const short4v* p1 = (const short4v*)(part + PART_ELEMS);
  const short4v* p2 = (const short4v*)(part + 2 * (size_t)PART_ELEMS);
  float4* o4 = (float4*)out;
  for (int i = blockIdx.x * 256 + threadIdx.x; i < n4; i += gridDim.x * 256) {
    float4 a = o4[i];
    const short4v q0 = p0[i], q1 = p1[i], q2 = p2[i];
    a.x += b2f((unsigned short)q0[0]) + b2f((unsigned short)q1[0]) + b2f((unsigned short)q2[0]);
    a.y += b2f((unsigned short)q0[1]) + b2f((unsigned short)q1[1]) + b2f((unsigned short)q2[1]);
    a.z += b2f((unsigned short)q0[2]) + b2f((unsigned short)q1[2]) + b2f((unsigned short)q2[2]);
    a.w += b2f((unsigned short)q0[3]) + b2f((unsigned short)q1[3]) + b2f((unsigned short)q2[3]);
    o4[i] = a;
  }
}

// out += f32 partial (mid fallback)
__global__ void __launch_bounds__(256) reduce_add(const float* __restrict__ part,
                                                  float* __restrict__ out) {
  const int n4 = PART_ELEMS / 4;
  const float4* p4 = (const float4*)part;
  float4* o4 = (float4*)out;
  for (int i = blockIdx.x * 256 + threadIdx.x; i < n4; i += gridDim.x * 256) {
    float4 a = o4[i];
    const float4 b = p4[i];
    a.x += b.x; a.y += b.y; a.z += b.z; a.w += b.w;
    o4[i] = a;
  }
}

__device__ __forceinline__ f32x4 MFMA(short8 a, short8 b, f32x4 c) {
  return __builtin_amdgcn_mfma_f32_16x16x32_bf16(a, b, c, 0, 0, 0);
}

// ======== GEMM v7: 256x256, KS=4, 8 waves 128x64, B direct-to-register ========
__global__ void __launch_bounds__(512, 2) kan_gemm_bd(
    const short* __restrict__ aimg, const short* __restrict__ bfimg,
    const float* __restrict__ bias, float* __restrict__ out,
    short* __restrict__ part) {
  constexpr int KT = NSTEPS / 4;                 // 18 K-tiles per block
  __shared__ __align__(16) short A_lds[2][256 * BK];   // 64 KB total LDS

  const int t = threadIdx.x, lane = t & 63, wid = t >> 6;  // 8 waves
  const int wm = wid >> 2, wn = wid & 3;                   // 2x4: 128m x 64n
  const int l15 = lane & 15, kb = lane >> 4;
  const int mb = blockIdx.x, nt = blockIdx.y;
  const int ks = blockIdx.z;
  const int m0 = mb * 256, n0 = nt * 256, s0 = ks * KT;

  f32x4 acc[8][4];
#pragma unroll
  for (int i = 0; i < 8; ++i)
#pragma unroll
    for (int j = 0; j < 4; ++j) acc[i][j] = (f32x4){0.f, 0.f, 0.f, 0.f};

  const short* bfbase = bfimg + (size_t)nt * NSTEPS * BCH2 * 8;

  // A: 2048 chunks (4 panels of 64 rows); identity chunk mapping -> LDS row = tile row.
  auto stageA = [&](int kt, int buf) {           // exactly 4 glds/thread
#pragma unroll
    for (int c = 0; c < 4; ++c) {
      const short* src = aimg +
          (((size_t)(4 * mb + c) * NSTEPS + kt) * ACH + wid * 64 + lane) * 8;
      glds16(src, &A_lds[buf][(c * 512 + wid * 64) * 8]);
    }
  };

  // B: 8 frag loads/thread straight to registers (reg idx = kk*4+fj).
  auto loadB = [&](int kt, short8* Bs) {
    const short* base = bfbase + (size_t)kt * BCH2 * 8;
#pragma unroll
    for (int kk = 0; kk < 2; ++kk)
#pragma unroll
      for (int fj = 0; fj < 4; ++fj)
        Bs[kk * 4 + fj] =
            *(const short8*)&base[((((wn * 4 + fj) * 2 + kk) * 64) + lane) * 8];
  };

  // 64 MFMA per wave per tile; A frags from LDS (swizzled), B from registers.
  auto mma_tile = [&](const short* __restrict__ Ab, const short8* Bs) {
#pragma unroll
    for (int kk = 0; kk < 2; ++kk) {
      const int sk = kk * 4 + kb;
      short8 af[8];
#pragma unroll
      for (int fi = 0; fi < 8; ++fi) {
        const int r = wm * 128 + fi * 16 + l15;
        af[fi] = *(const short8*)&Ab[r * 64 + (sk ^ (r & 7)) * 8];
      }
#pragma unroll
      for (int fi = 0; fi < 8; ++fi)
#pragma unroll
        for (int fj = 0; fj < 4; ++fj)
          acc[fi][fj] = MFMA(af[fi], Bs[kk * 4 + fj], acc[fi][fj]);
    }
  };

  short8 B0[8], B1[8];

  // ---- prologue: tile 0 in flight (12 VMEM) ----
  stageA(s0, 0);
  loadB(s0, B0);

#define KAN_TILE(TL, BCUR, BNXT)                                              \
  {                                                                           \
    const int tl = (TL);                                                      \
    const int b = tl & 1;                                                     \
    if (tl + 1 < KT) {                                                        \
      stageA(s0 + tl + 1, b ^ 1);                                             \
      loadB(s0 + tl + 1, BNXT);                                               \
      asm volatile("s_waitcnt vmcnt(12)" ::: "memory");                       \
    } else {                                                                  \
      asm volatile("s_waitcnt vmcnt(0)" ::: "memory");                        \
    }                                                                         \
    __builtin_amdgcn_s_barrier();                                             \
    mma_tile(&A_lds[b][0], BCUR);                                             \
    __builtin_amdgcn_s_barrier();                                             \
  }

  for (int tt = 0; tt < KT; tt += 2) {
    KAN_TILE(tt, B0, B1)
    KAN_TILE(tt + 1, B1, B0)
  }
#undef KAN_TILE

  // ---- epilogue: ks=0 -> out+bias; ks 1..3 -> bf16 partial plane ks-1 ----
#pragma unroll
  for (int fj = 0; fj < 4; ++fj) {
    const int col = n0 + wn * 64 + fj * 16 + l15;
    const float bb = (ks == 0) ? bias[col] : 0.f;
#pragma unroll
    for (int fi = 0; fi < 8; ++fi) {
      const int rb = m0 + wm * 128 + fi * 16 + kb * 4;
#pragma unroll
      for (int r4 = 0; r4 < 4; ++r4) {
        const size_t idx = (size_t)(rb + r4) * OUT_F + col;
        if (ks == 0) out[idx] = acc[fi][fj][r4] + bb;
        else         part[(size_t)(ks - 1) * PART_ELEMS + idx] = f2bf(acc[fi][fj][r4]);
      }
    }
  }
}

// ======== mid fallback: R13-proven 64x256 counted-vmcnt GEMM ========
template <int KS>
__global__ void __launch_bounds__(512, 4) kan_gemm_mid(
    const short* __restrict__ aimg, const short* __restrict__ bimg,
    const float* __restrict__ bias, float* __restrict__ out,
    float* __restrict__ part) {
  constexpr int SPLC = NSTEPS / KS;
  __shared__ __align__(16) short A_lds[2][64 * BK];
  __shared__ __align__(16) short B_lds[2][256 * BK];

  const int t = threadIdx.x, lane = t & 63, wid = t >> 6;
  const int wm = wid >> 2, wn = wid & 3;
  const int l15 = lane & 15, kb = lane >> 4;
  const int mb = blockIdx.x, nt = blockIdx.y;
  const int ks = (KS > 1) ? blockIdx.z : 0;
  const int m0 = mb * 64, n0 = nt * 256, s0 = ks * SPLC;

  f32x4 acc[2][4];
#pragma unroll
  for (int i = 0; i < 2; ++i)
#pragma unroll
    for (int j = 0; j < 4; ++j) acc[i][j] = (f32x4){0.f, 0.f, 0.f, 0.f};

  const short* abase = aimg + (size_t)mb * NSTEPS * ACH * 8;
  const short* bbase = bimg + (size_t)nt * NSTEPS * BCH2 * 8;

  auto stage = [&](int s, int buf) {
    const short* as = abase + ((size_t)s * ACH + wid * 64 + lane) * 8;
    glds16(as, &A_lds[buf][wid * 512]);
    const short* bs = bbase + ((size_t)s * BCH2 + wid * 64 + lane) * 8;
#pragma unroll
    for (int c2 = 0; c2 < 4; ++c2)
      glds16(bs + (size_t)c2 * 512 * 8, &B_lds[buf][c2 * 4096 + wid * 512]);
  };

  auto mfma_step = [&](int buf) {
#pragma unroll
    for (int kk = 0; kk < 2; ++kk) {
      const int sk = kk * 4 + kb;
      short8 af[2], bf[4];
#pragma unroll
      for (int mi = 0; mi < 2; ++mi) {
        const int r = wm * 32 + mi * 16 + l15;
        af[mi] = *(const short8*)&A_lds[buf][r * BK + (sk ^ (r & 7)) * 8];
      }
#pragma unroll
      for (int ni = 0; ni < 4; ++ni) {
        const int n = wn * 64 + ni * 16 + l15;
        bf[ni] = *(const short8*)&B_lds[buf][n * BK + (sk ^ (n & 7)) * 8];
      }
#pragma unroll
      for (int mi = 0; mi < 2; ++mi)
#pragma unroll
        for (int ni = 0; ni < 4; ++ni)
          acc[mi][ni] = MFMA(af[mi], bf[ni], acc[mi][ni]);
    }
  };

  stage(s0, 0);
  for (int si = 0; si < SPLC; ++si) {
    const int c = si & 1;
    if (si + 1 < SPLC) {
      stage(s0 + si + 1, c ^ 1);
      asm volatile("s_waitcnt vmcnt(5)" ::: "memory");
    } else {
      asm volatile("s_waitcnt vmcnt(0)" ::: "memory");
    }
    __builtin_amdgcn_s_barrier();
    mfma_step(c);
    __builtin_amdgcn_s_barrier();
  }

#pragma unroll
  for (int ni = 0; ni < 4; ++ni) {
    const int col = n0 + wn * 64 + ni * 16 + l15;
    const float bb = (KS == 1 || ks == 0) ? bias[col] : 0.f;
#pragma unroll
    for (int mi = 0; mi < 2; ++mi) {
      const int rb = m0 + wm * 32 + mi * 16 + kb * 4;
#pragma unroll
      for (int r4 = 0; r4 < 4; ++r4) {
        const size_t idx = (size_t)(rb + r4) * OUT_F + col;
        if (KS == 1 || ks == 0) out[idx] = acc[mi][ni][r4] + bb;
        else                    part[idx] = acc[mi][ni][r4];
      }
    }
  }
}

extern "C" void kernel_launch(void* const* d_in, const int* in_sizes, int n_in,
                              void* d_out, int out_size, void* d_ws, size_t ws_size,
                              hipStream_t stream) {
  const float* x    = (const float*)d_in[0];
  const float* rw   = (const float*)d_in[1];
  const float* rc   = (const float*)d_in[2];
  const float* w    = (const float*)d_in[3];
  const float* bias = (const float*)d_in[4];
  const float* sb   = (const float*)d_in[5];
  float* out = (float*)d_out;

  const int nrows = in_sizes[0] / IN_F;  // 8192
  const int npan = nrows / PAN;          // 128 A panels

  const size_t b_bytes     = (size_t)NT2 * NSTEPS * BCH2 * 16;       // 4.72 MB
  const size_t aimg_bytes  = (size_t)npan * NSTEPS * ACH * 16;       // 75.5 MB
  const size_t bf16p_bytes = (size_t)3 * PART_ELEMS * sizeof(short); // 25.2 MB
  const size_t f32p_bytes  = (size_t)PART_ELEMS * sizeof(float);     // 16.8 MB
  const int bch_total = NT2 * NSTEPS * BCH2;

  if (ws_size >= b_bytes + aimg_bytes + bf16p_bytes) {
    short* bimg = (short*)d_ws;
    short* aimg = (short*)((char*)d_ws + b_bytes);
    short* part = (short*)((char*)d_ws + b_bytes + aimg_bytes);
    prep_bf<<<bch_total / 256, 256, 0, stream>>>(w, sb, bimg);
    prep_a<<<npan * NSTEPS * ACH / 256, 256, 0, stream>>>(x, rw, rc, aimg);
    kan_gemm_bd<<<dim3(nrows / 256, 2, 4), 512, 0, stream>>>(aimg, bimg, bias, out, part);
    reduce3b<<<2048, 256, 0, stream>>>(part, out);
  } else if (ws_size >= b_bytes + aimg_bytes + f32p_bytes) {
    short* bimg = (short*)d_ws;
    short* aimg = (short*)((char*)d_ws + b_bytes);
    float* part = (float*)((char*)d_ws + b_bytes + aimg_bytes);
    prep_b2<<<bch_total / 256, 256, 0, stream>>>(w, sb, bimg);
    prep_a<<<npan * NSTEPS * ACH / 256, 256, 0, stream>>>(x, rw, rc, aimg);
    kan_gemm_mid<2><<<dim3(nrows / 64, 2, 2), 512, 0, stream>>>(aimg, bimg, bias, out, part);
    reduce_add<<<2048, 256, 0, stream>>>(part, out);
  } else if (ws_size >= b_bytes + aimg_bytes) {
    short* bimg = (short*)d_ws;
    short* aimg = (short*)((char*)d_ws + b_bytes);
    prep_b2<<<bch_total / 256, 256, 0, stream>>>(w, sb, bimg);
    prep_a<<<npan * NSTEPS * ACH / 256, 256, 0, stream>>>(x, rw, rc, aimg);
    kan_gemm_mid<1><<<dim3(nrows / 64, 2, 1), 512, 0, stream>>>(aimg, bimg, bias, out, nullptr);
  } else {
    short* bimg = (short*)d_ws;
    prep_b2<<<bch_total / 256, 256, 0, stream>>>(w, sb, bimg);
    kan_gemm_mid<1><<<dim3(nrows / 64, 2, 1), 512, 0, stream>>>(nullptr, bimg, bias, out, nullptr);
  }
}

// Round 23
// 113.729 us; speedup vs baseline: 1.0002x; 1.0002x over previous
//
#include <hip/hip_runtime.h>
#include <hip/hip_bf16.h>

typedef __attribute__((ext_vector_type(8))) short short8;
typedef __attribute__((ext_vector_type(4))) float f32x4;

#define IN_F 512
#define OUT_F 512
#define BK 64
#define PHI_STEPS 64
#define NSTEPS 72
#define PAN 64                           // A image panel = 64 rows
#define ACH 512                          // A chunks per (panel, step)
#define BCH2 2048                        // B chunks per (nt256, step) (both layouts)
#define NT2 2
#define PART_ELEMS (8192 * OUT_F)
#define C2 (-10.2591705f)                // -(8/3)^2 * log2(e)

// Branchless RNE f32->bf16 (finite values only)
__device__ __forceinline__ short f2bf(float f) {
  unsigned u = __builtin_bit_cast(unsigned, f);
  u += 0x7fffu + ((u >> 16) & 1u);
  return (short)(u >> 16);
}
__device__ __forceinline__ float b2f(unsigned short u) {
  return __builtin_bit_cast(float, (unsigned)u << 16);
}

__device__ __forceinline__ void glds16(const void* g, void* l) {
  // 16B global->LDS; LDS base wave-uniform (HW adds lane*16); global src per-lane.
  __builtin_amdgcn_global_load_lds(
      (const __attribute__((address_space(1))) unsigned int*)g,
      (__attribute__((address_space(3))) unsigned int*)l, 16, 0, 0);
}

__device__ __forceinline__ float bsrc(const float* __restrict__ w,
                                      const float* __restrict__ sb,
                                      int k, int col) {
  return (k < IN_F * 8) ? w[(size_t)k * OUT_F + col]
                        : sb[(size_t)(k - IN_F * 8) * OUT_F + col];
}

// ---- B frag-image (for B-direct GEMM): per (nt,kt), chunk ci = (c*2+kk)*64+lane,
//      c = wn*4+fj (0..15); element j -> B[k=kt*64+(kk*4+(lane>>4))*8+j]
//                                        [nt*256 + c*16 + (lane&15)].
__global__ void __launch_bounds__(256) prep_bf(const float* __restrict__ w,
                                               const float* __restrict__ sb,
                                               short* __restrict__ img) {
  const int D = blockIdx.x * 256 + threadIdx.x;
  const int ci = D & (BCH2 - 1);
  const int im = D >> 11;
  const int s = im % NSTEPS;
  const int nt = im / NSTEPS;
  const int lane = ci & 63;
  const int kk = (ci >> 6) & 1;
  const int c = ci >> 7;                 // 0..15
  const int col = nt * 256 + c * 16 + (lane & 15);
  const int kbase = s * 64 + (kk * 4 + (lane >> 4)) * 8;
  short8 v;
#pragma unroll
  for (int j = 0; j < 8; ++j) v[j] = f2bf(bsrc(w, sb, kbase + j, col));
  *(short8*)&img[(size_t)D * 8] = v;
}

// ---- old-layout B images (mid fallback): chunk ci=n*8+slot, slot=oct^(n&7)
__global__ void __launch_bounds__(256) prep_b2(const float* __restrict__ w,
                                               const float* __restrict__ sb,
                                               short* __restrict__ img) {
  const int D = blockIdx.x * 256 + threadIdx.x;
  const int ci = D & (BCH2 - 1);
  const int im = D >> 11;
  const int s = im % NSTEPS;
  const int nt = im / NSTEPS;
  const int n = ci >> 3, slot = ci & 7;
  const int oct = slot ^ (n & 7);
  const int col = nt * 256 + n;
  short8 v;
#pragma unroll
  for (int j = 0; j < 8; ++j) v[j] = f2bf(bsrc(w, sb, s * 64 + oct * 8 + j, col));
  *(short8*)&img[(size_t)D * 8] = v;
}

// ---- A images: per (panel,s), chunk ci=m*8+slot, slot=oct^(m&7);
//      element j -> phi[panel*64+m][k=s*64+oct*8+j].
__global__ void __launch_bounds__(256) prep_a(const float* __restrict__ x,
                                              const float* __restrict__ rw,
                                              const float* __restrict__ rc,
                                              short* __restrict__ aimg) {
  const int D = blockIdx.x * 256 + threadIdx.x;
  const int ci = D & (ACH - 1);
  const int rest = D >> 9;
  const int s = rest % NSTEPS;
  const int pan = rest / NSTEPS;
  const int m = ci >> 3, slot = ci & 7;
  const int oct = slot ^ (m & 7);
  const int row = pan * PAN + m;
  short8 v;
  if (s < PHI_STEPS) {
    const int feat = s * 8 + oct;
    const float xv = x[(size_t)row * IN_F + feat];
    const float4 r0 = *(const float4*)(rw + feat * 8);
    const float4 r1 = *(const float4*)(rw + feat * 8 + 4);
    const float4 q0 = *(const float4*)(rc + feat * 8);
    const float4 q1 = *(const float4*)(rc + feat * 8 + 4);
    const float rwv[8] = {r0.x, r0.y, r0.z, r0.w, r1.x, r1.y, r1.z, r1.w};
    const float rcv[8] = {q0.x, q0.y, q0.z, q0.w, q1.x, q1.y, q1.z, q1.w};
#pragma unroll
    for (int j = 0; j < 8; ++j) {
      const float z = fmaf(xv, rwv[j], -rcv[j]);
      v[j] = f2bf(exp2f(C2 * z * z));
    }
  } else {
    const float* xp = x + (size_t)row * IN_F + (s - PHI_STEPS) * 64 + oct * 8;
    const float4 u0 = *(const float4*)xp, u1 = *(const float4*)(xp + 4);
    v[0] = f2bf(__cosf(u0.x)); v[1] = f2bf(__cosf(u0.y));
    v[2] = f2bf(__cosf(u0.z)); v[3] = f2bf(__cosf(u0.w));
    v[4] = f2bf(__cosf(u1.x)); v[5] = f2bf(__cosf(u1.y));
    v[6] = f2bf(__cosf(u1.z)); v[7] = f2bf(__cosf(u1.w));
  }
  *(short8*)&aimg[(size_t)D * 8] = v;
}

// out += bf16 partials p0+p1+p2
__global__ void __launch_bounds__(256) reduce3b(const short* __restrict__ part,
                                                float* __restrict__ out) {
  typedef __attribute__((ext_vector_type(4))) short short4v;
  const int n4 = PART_ELEMS / 4;
  const short4v* p0 = (const short4v*)part;
  const short4v* p1 = (const short4v*)(part + PART_ELEMS);
  const short4v* p2 = (const short4v*)(part + 2 * (size_t)PART_ELEMS);
  float4* o4 = (float4*)out;
  for (int i = blockIdx.x * 256 + threadIdx.x; i < n4; i += gridDim.x * 256) {
    float4 a = o4[i];
    const short4v q0 = p0[i], q1 = p1[i], q2 = p2[i];
    a.x += b2f((unsigned short)q0[0]) + b2f((unsigned short)q1[0]) + b2f((unsigned short)q2[0]);
    a.y += b2f((unsigned short)q0[1]) + b2f((unsigned short)q1[1]) + b2f((unsigned short)q2[1]);
    a.z += b2f((unsigned short)q0[2]) + b2f((unsigned short)q1[2]) + b2f((unsigned short)q2[2]);
    a.w += b2f((unsigned short)q0[3]) + b2f((unsigned short)q1[3]) + b2f((unsigned short)q2[3]);
    o4[i] = a;
  }
}

// out += f32 partial (mid fallback)
__global__ void __launch_bounds__(256) reduce_add(const float* __restrict__ part,
                                                  float* __restrict__ out) {
  const int n4 = PART_ELEMS / 4;
  const float4* p4 = (const float4*)part;
  float4* o4 = (float4*)out;
  for (int i = blockIdx.x * 256 + threadIdx.x; i < n4; i += gridDim.x * 256) {
    float4 a = o4[i];
    const float4 b = p4[i];
    a.x += b.x; a.y += b.y; a.z += b.z; a.w += b.w;
    o4[i] = a;
  }
}

__device__ __forceinline__ f32x4 MFMA(short8 a, short8 b, f32x4 c) {
  return __builtin_amdgcn_mfma_f32_16x16x32_bf16(a, b, c, 0, 0, 0);
}

// ======== GEMM v7b: 256x256, KS=4, 8 waves 128x64, B direct-to-register ========
// (R22 structure; frag arrays passed BY REFERENCE so they stay in VGPRs — rule #20)
__global__ void __launch_bounds__(512, 2) kan_gemm_bd(
    const short* __restrict__ aimg, const short* __restrict__ bfimg,
    const float* __restrict__ bias, float* __restrict__ out,
    short* __restrict__ part) {
  constexpr int KT = NSTEPS / 4;                 // 18 K-tiles per block
  __shared__ __align__(16) short A_lds[2][256 * BK];   // 64 KB total LDS

  const int t = threadIdx.x, lane = t & 63, wid = t >> 6;  // 8 waves
  const int wm = wid >> 2, wn = wid & 3;                   // 2x4: 128m x 64n
  const int l15 = lane & 15, kb = lane >> 4;
  const int mb = blockIdx.x, nt = blockIdx.y;
  const int ks = blockIdx.z;
  const int m0 = mb * 256, n0 = nt * 256, s0 = ks * KT;

  f32x4 acc[8][4];
#pragma unroll
  for (int i = 0; i < 8; ++i)
#pragma unroll
    for (int j = 0; j < 4; ++j) acc[i][j] = (f32x4){0.f, 0.f, 0.f, 0.f};

  const short* bfbase = bfimg + (size_t)nt * NSTEPS * BCH2 * 8;

  // A: 2048 chunks (4 panels of 64 rows); identity chunk mapping -> LDS row = tile row.
  auto stageA = [&](int kt, int buf) {           // exactly 4 glds/thread
#pragma unroll
    for (int c = 0; c < 4; ++c) {
      const short* src = aimg +
          (((size_t)(4 * mb + c) * NSTEPS + kt) * ACH + wid * 64 + lane) * 8;
      glds16(src, &A_lds[buf][(c * 512 + wid * 64) * 8]);
    }
  };

  // B: 8 frag loads/thread straight to registers (reg idx = kk*4+fj).
  // Reference-to-array parameter keeps Bs in VGPRs (pointer param demotes to scratch).
  auto loadB = [&](int kt, short8 (&Bs)[8]) {
    const short* base = bfbase + (size_t)kt * BCH2 * 8;
#pragma unroll
    for (int kk = 0; kk < 2; ++kk)
#pragma unroll
      for (int fj = 0; fj < 4; ++fj)
        Bs[kk * 4 + fj] =
            *(const short8*)&base[((((wn * 4 + fj) * 2 + kk) * 64) + lane) * 8];
  };

  // 64 MFMA per wave per tile; A frags from LDS (swizzled), B from registers.
  auto mma_tile = [&](const short* __restrict__ Ab, const short8 (&Bs)[8]) {
#pragma unroll
    for (int kk = 0; kk < 2; ++kk) {
      const int sk = kk * 4 + kb;
      short8 af[8];
#pragma unroll
      for (int fi = 0; fi < 8; ++fi) {
        const int r = wm * 128 + fi * 16 + l15;
        af[fi] = *(const short8*)&Ab[r * 64 + (sk ^ (r & 7)) * 8];
      }
#pragma unroll
      for (int fi = 0; fi < 8; ++fi)
#pragma unroll
        for (int fj = 0; fj < 4; ++fj)
          acc[fi][fj] = MFMA(af[fi], Bs[kk * 4 + fj], acc[fi][fj]);
    }
  };

  short8 B0[8], B1[8];

  // ---- prologue: tile 0 in flight (12 VMEM) ----
  stageA(s0, 0);
  loadB(s0, B0);

#define KAN_TILE(TL, BCUR, BNXT)                                              \
  {                                                                           \
    const int tl = (TL);                                                      \
    const int b = tl & 1;                                                     \
    if (tl + 1 < KT) {                                                        \
      stageA(s0 + tl + 1, b ^ 1);                                             \
      loadB(s0 + tl + 1, BNXT);                                               \
      asm volatile("s_waitcnt vmcnt(12)" ::: "memory");                       \
    } else {                                                                  \
      asm volatile("s_waitcnt vmcnt(0)" ::: "memory");                        \
    }                                                                         \
    __builtin_amdgcn_s_barrier();                                             \
    mma_tile(&A_lds[b][0], BCUR);                                             \
    __builtin_amdgcn_s_barrier();                                             \
  }

  for (int tt = 0; tt < KT; tt += 2) {
    KAN_TILE(tt, B0, B1)
    KAN_TILE(tt + 1, B1, B0)
  }
#undef KAN_TILE

  // ---- epilogue: ks=0 -> out+bias; ks 1..3 -> bf16 partial plane ks-1 ----
#pragma unroll
  for (int fj = 0; fj < 4; ++fj) {
    const int col = n0 + wn * 64 + fj * 16 + l15;
    const float bb = (ks == 0) ? bias[col] : 0.f;
#pragma unroll
    for (int fi = 0; fi < 8; ++fi) {
      const int rb = m0 + wm * 128 + fi * 16 + kb * 4;
#pragma unroll
      for (int r4 = 0; r4 < 4; ++r4) {
        const size_t idx = (size_t)(rb + r4) * OUT_F + col;
        if (ks == 0) out[idx] = acc[fi][fj][r4] + bb;
        else         part[(size_t)(ks - 1) * PART_ELEMS + idx] = f2bf(acc[fi][fj][r4]);
      }
    }
  }
}

// ======== mid fallback: R13-proven 64x256 counted-vmcnt GEMM ========
template <int KS>
__global__ void __launch_bounds__(512, 4) kan_gemm_mid(
    const short* __restrict__ aimg, const short* __restrict__ bimg,
    const float* __restrict__ bias, float* __restrict__ out,
    float* __restrict__ part) {
  constexpr int SPLC = NSTEPS / KS;
  __shared__ __align__(16) short A_lds[2][64 * BK];
  __shared__ __align__(16) short B_lds[2][256 * BK];

  const int t = threadIdx.x, lane = t & 63, wid = t >> 6;
  const int wm = wid >> 2, wn = wid & 3;
  const int l15 = lane & 15, kb = lane >> 4;
  const int mb = blockIdx.x, nt = blockIdx.y;
  const int ks = (KS > 1) ? blockIdx.z : 0;
  const int m0 = mb * 64, n0 = nt * 256, s0 = ks * SPLC;

  f32x4 acc[2][4];
#pragma unroll
  for (int i = 0; i < 2; ++i)
#pragma unroll
    for (int j = 0; j < 4; ++j) acc[i][j] = (f32x4){0.f, 0.f, 0.f, 0.f};

  const short* abase = aimg + (size_t)mb * NSTEPS * ACH * 8;
  const short* bbase = bimg + (size_t)nt * NSTEPS * BCH2 * 8;

  auto stage = [&](int s, int buf) {
    const short* as = abase + ((size_t)s * ACH + wid * 64 + lane) * 8;
    glds16(as, &A_lds[buf][wid * 512]);
    const short* bs = bbase + ((size_t)s * BCH2 + wid * 64 + lane) * 8;
#pragma unroll
    for (int c2 = 0; c2 < 4; ++c2)
      glds16(bs + (size_t)c2 * 512 * 8, &B_lds[buf][c2 * 4096 + wid * 512]);
  };

  auto mfma_step = [&](int buf) {
#pragma unroll
    for (int kk = 0; kk < 2; ++kk) {
      const int sk = kk * 4 + kb;
      short8 af[2], bf[4];
#pragma unroll
      for (int mi = 0; mi < 2; ++mi) {
        const int r = wm * 32 + mi * 16 + l15;
        af[mi] = *(const short8*)&A_lds[buf][r * BK + (sk ^ (r & 7)) * 8];
      }
#pragma unroll
      for (int ni = 0; ni < 4; ++ni) {
        const int n = wn * 64 + ni * 16 + l15;
        bf[ni] = *(const short8*)&B_lds[buf][n * BK + (sk ^ (n & 7)) * 8];
      }
#pragma unroll
      for (int mi = 0; mi < 2; ++mi)
#pragma unroll
        for (int ni = 0; ni < 4; ++ni)
          acc[mi][ni] = MFMA(af[mi], bf[ni], acc[mi][ni]);
    }
  };

  stage(s0, 0);
  for (int si = 0; si < SPLC; ++si) {
    const int c = si & 1;
    if (si + 1 < SPLC) {
      stage(s0 + si + 1, c ^ 1);
      asm volatile("s_waitcnt vmcnt(5)" ::: "memory");
    } else {
      asm volatile("s_waitcnt vmcnt(0)" ::: "memory");
    }
    __builtin_amdgcn_s_barrier();
    mfma_step(c);
    __builtin_amdgcn_s_barrier();
  }

#pragma unroll
  for (int ni = 0; ni < 4; ++ni) {
    const int col = n0 + wn * 64 + ni * 16 + l15;
    const float bb = (KS == 1 || ks == 0) ? bias[col] : 0.f;
#pragma unroll
    for (int mi = 0; mi < 2; ++mi) {
      const int rb = m0 + wm * 32 + mi * 16 + kb * 4;
#pragma unroll
      for (int r4 = 0; r4 < 4; ++r4) {
        const size_t idx = (size_t)(rb + r4) * OUT_F + col;
        if (KS == 1 || ks == 0) out[idx] = acc[mi][ni][r4] + bb;
        else                    part[idx] = acc[mi][ni][r4];
      }
    }
  }
}

extern "C" void kernel_launch(void* const* d_in, const int* in_sizes, int n_in,
                              void* d_out, int out_size, void* d_ws, size_t ws_size,
                              hipStream_t stream) {
  const float* x    = (const float*)d_in[0];
  const float* rw   = (const float*)d_in[1];
  const float* rc   = (const float*)d_in[2];
  const float* w    = (const float*)d_in[3];
  const float* bias = (const float*)d_in[4];
  const float* sb   = (const float*)d_in[5];
  float* out = (float*)d_out;

  const int nrows = in_sizes[0] / IN_F;  // 8192
  const int npan = nrows / PAN;          // 128 A panels

  const size_t b_bytes     = (size_t)NT2 * NSTEPS * BCH2 * 16;       // 4.72 MB
  const size_t aimg_bytes  = (size_t)npan * NSTEPS * ACH * 16;       // 75.5 MB
  const size_t bf16p_bytes = (size_t)3 * PART_ELEMS * sizeof(short); // 25.2 MB
  const size_t f32p_bytes  = (size_t)PART_ELEMS * sizeof(float);     // 16.8 MB
  const int bch_total = NT2 * NSTEPS * BCH2;

  if (ws_size >= b_bytes + aimg_bytes + bf16p_bytes) {
    short* bimg = (short*)d_ws;
    short* aimg = (short*)((char*)d_ws + b_bytes);
    short* part = (short*)((char*)d_ws + b_bytes + aimg_bytes);
    prep_bf<<<bch_total / 256, 256, 0, stream>>>(w, sb, bimg);
    prep_a<<<npan * NSTEPS * ACH / 256, 256, 0, stream>>>(x, rw, rc, aimg);
    kan_gemm_bd<<<dim3(nrows / 256, 2, 4), 512, 0, stream>>>(aimg, bimg, bias, out, part);
    reduce3b<<<2048, 256, 0, stream>>>(part, out);
  } else if (ws_size >= b_bytes + aimg_bytes + f32p_bytes) {
    short* bimg = (short*)d_ws;
    short* aimg = (short*)((char*)d_ws + b_bytes);
    float* part = (float*)((char*)d_ws + b_bytes + aimg_bytes);
    prep_b2<<<bch_total / 256, 256, 0, stream>>>(w, sb, bimg);
    prep_a<<<npan * NSTEPS * ACH / 256, 256, 0, stream>>>(x, rw, rc, aimg);
    kan_gemm_mid<2><<<dim3(nrows / 64, 2, 2), 512, 0, stream>>>(aimg, bimg, bias, out, part);
    reduce_add<<<2048, 256, 0, stream>>>(part, out);
  } else if (ws_size >= b_bytes + aimg_bytes) {
    short* bimg = (short*)d_ws;
    short* aimg = (short*)((char*)d_ws + b_bytes);
    prep_b2<<<bch_total / 256, 256, 0, stream>>>(w, sb, bimg);
    prep_a<<<npan * NSTEPS * ACH / 256, 256, 0, stream>>>(x, rw, rc, aimg);
    kan_gemm_mid<1><<<dim3(nrows / 64, 2, 1), 512, 0, stream>>>(aimg, bimg, bias, out, nullptr);
  } else {
    short* bimg = (short*)d_ws;
    prep_b2<<<bch_total / 256, 256, 0, stream>>>(w, sb, bimg);
    kan_gemm_mid<1><<<dim3(nrows / 64, 2, 1), 512, 0, stream>>>(nullptr, bimg, bias, out, nullptr);
  }
}

// Round 24
// 100.307 us; speedup vs baseline: 1.1341x; 1.1338x over previous
//
#include <hip/hip_runtime.h>
#include <hip/hip_bf16.h>

typedef __attribute__((ext_vector_type(8))) short short8;
typedef __attribute__((ext_vector_type(4))) float f32x4;

#define IN_F 512
#define OUT_F 512
#define PHI_STEPS 64
#define NSTEPS 72
#define BCH2 2048                        // B chunks per (nt256, step)
#define NT2 2
#define KT 18                            // K-tiles per block (KS=4)
#define PART_ELEMS (8192 * OUT_F)
#define C2 (-10.2591705f)                // -(8/3)^2 * log2(e)

__device__ __forceinline__ short f2bf(float f) {
  unsigned u = __builtin_bit_cast(unsigned, f);
  u += 0x7fffu + ((u >> 16) & 1u);
  return (short)(u >> 16);
}
__device__ __forceinline__ float b2f(unsigned short u) {
  return __builtin_bit_cast(float, (unsigned)u << 16);
}

__device__ __forceinline__ void glds16(const void* g, void* l) {
  __builtin_amdgcn_global_load_lds(
      (const __attribute__((address_space(1))) unsigned int*)g,
      (__attribute__((address_space(3))) unsigned int*)l, 16, 0, 0);
}
__device__ __forceinline__ void glds4(const void* g, void* l) {
  __builtin_amdgcn_global_load_lds(
      (const __attribute__((address_space(1))) unsigned int*)g,
      (__attribute__((address_space(3))) unsigned int*)l, 4, 0, 0);
}

__device__ __forceinline__ float bsrc(const float* __restrict__ w,
                                      const float* __restrict__ sb,
                                      int k, int col) {
  return (k < IN_F * 8) ? w[(size_t)k * OUT_F + col]
                        : sb[(size_t)(k - IN_F * 8) * OUT_F + col];
}

// ---- B images (R13/R19-proven layout): per (nt,s), chunk ci=n*8+slot,
//      slot = oct^(n&7); element j -> B[k=s*64+oct*8+j][nt*256+n].
__global__ void __launch_bounds__(256) prep_b2(const float* __restrict__ w,
                                               const float* __restrict__ sb,
                                               short* __restrict__ img) {
  const int D = blockIdx.x * 256 + threadIdx.x;
  const int ci = D & (BCH2 - 1);
  const int im = D >> 11;
  const int s = im % NSTEPS;
  const int nt = im / NSTEPS;
  const int n = ci >> 3, slot = ci & 7;
  const int oct = slot ^ (n & 7);
  const int col = nt * 256 + n;
  short8 v;
#pragma unroll
  for (int j = 0; j < 8; ++j) v[j] = f2bf(bsrc(w, sb, s * 64 + oct * 8 + j, col));
  *(short8*)&img[(size_t)D * 8] = v;
}

// ---- x-image: ximg[s][oct][row] = x[row][s*8+oct], s<64. LDS-transposed,
//      coalesced both sides. Block = (s-pair s2, row-block of 256).
__global__ void __launch_bounds__(256) prep_x(const float* __restrict__ x,
                                              float* __restrict__ ximg) {
  __shared__ float T[256][17];
  const int t = threadIdx.x;
  const int s2 = blockIdx.x;        // 0..31 -> steps 2*s2, 2*s2+1
  const int blk = blockIdx.y;       // 0..31 -> rows blk*256..
#pragma unroll
  for (int rep = 0; rep < 4; ++rep) {
    const int row = rep * 64 + (t >> 2);
    const int p = t & 3;
    const float4 v = *(const float4*)&x[(size_t)(blk * 256 + row) * IN_F + s2 * 16 + p * 4];
    T[row][p * 4 + 0] = v.x; T[row][p * 4 + 1] = v.y;
    T[row][p * 4 + 2] = v.z; T[row][p * 4 + 3] = v.w;
  }
  __syncthreads();
#pragma unroll
  for (int f = 0; f < 16; ++f) {
    const int s = 2 * s2 + (f >> 3), oct = f & 7;
    ximg[(size_t)s * 65536 + oct * 8192 + blk * 256 + t] = T[t][f];
  }
}

// out += bf16 partials p0+p1+p2
__global__ void __launch_bounds__(256) reduce3b(const short* __restrict__ part,
                                                float* __restrict__ out) {
  typedef __attribute__((ext_vector_type(4))) short short4v;
  const int n4 = PART_ELEMS / 4;
  const short4v* p0 = (const short4v*)part;
  const short4v* p1 = (const short4v*)(part + PART_ELEMS);
  const short4v* p2 = (const short4v*)(part + 2 * (size_t)PART_ELEMS);
  float4* o4 = (float4*)out;
  for (int i = blockIdx.x * 256 + threadIdx.x; i < n4; i += gridDim.x * 256) {
    float4 a = o4[i];
    const short4v q0 = p0[i], q1 = p1[i], q2 = p2[i];
    a.x += b2f((unsigned short)q0[0]) + b2f((unsigned short)q1[0]) + b2f((unsigned short)q2[0]);
    a.y += b2f((unsigned short)q0[1]) + b2f((unsigned short)q1[1]) + b2f((unsigned short)q2[1]);
    a.z += b2f((unsigned short)q0[2]) + b2f((unsigned short)q1[2]) + b2f((unsigned short)q2[2]);
    a.w += b2f((unsigned short)q0[3]) + b2f((unsigned short)q1[3]) + b2f((unsigned short)q2[3]);
    o4[i] = a;
  }
}

__device__ __forceinline__ f32x4 MFMA(short8 a, short8 b, f32x4 c) {
  return __builtin_amdgcn_mfma_f32_16x16x32_bf16(a, b, c, 0, 0, 0);
}

// ======== fused GEMM: 256x256, KS=4, 16 waves 64x64, phi generated in-kernel ====
// Per wave: k-octet oct = wid>>1 (params via s_load), row-half h = wid&1.
// vmcnt ring = pure glds: phi iter {2 X-glds + 2 B-glds}; cos tail direct loads.
__global__ void __launch_bounds__(1024, 4) kan_fx(
    const float* __restrict__ x, const float* __restrict__ ximg,
    const float* __restrict__ rw, const float* __restrict__ rc,
    const short* __restrict__ bimg, const float* __restrict__ bias,
    float* __restrict__ out, short* __restrict__ part) {
  __shared__ __align__(16) short A_lds[2][256 * 64];   // 64 KB
  __shared__ __align__(16) short B_lds[2][256 * 64];   // 64 KB
  __shared__ __align__(16) float X_lds[2][2048];       // 16 KB (144 total)

  const int t = threadIdx.x, lane = t & 63, wid = t >> 6;  // 16 waves
  const int wm = wid >> 2, wn = wid & 3;                   // 4x4, 64x64 each
  const int l15 = lane & 15, kb = lane >> 4;
  const int mb = blockIdx.x, nt = blockIdx.y, ks = blockIdx.z;
  const int m0 = mb * 256, n0 = nt * 256, s0 = ks * KT;

  const int octu = __builtin_amdgcn_readfirstlane(wid >> 1);  // wave k-octet (SGPR)
  const int h = wid & 1;
  const int r1 = h * 128 + lane, r2 = r1 + 64;  // this thread's two A rows

  f32x4 acc[4][4];
#pragma unroll
  for (int i = 0; i < 4; ++i)
#pragma unroll
    for (int j = 0; j < 4; ++j) acc[i][j] = (f32x4){0.f, 0.f, 0.f, 0.f};

  float rwv[8], rcv[8];   // params (uniform -> SGPRs)

  auto loadP = [&](int s1) {
    const int feat = s1 * 8 + octu;
#pragma unroll
    for (int j = 0; j < 8; ++j) { rwv[j] = rw[feat * 8 + j]; rcv[j] = rc[feat * 8 + j]; }
  };
  auto stageX = [&](int s1, int buf) {    // 2 glds4 (wave covers its 128 rows)
    const float* base = ximg + (size_t)s1 * 65536 + octu * 8192 + mb * 256 + h * 128;
    glds4(base + lane, &X_lds[buf][wid * 128]);
    glds4(base + 64 + lane, &X_lds[buf][wid * 128 + 64]);
  };
  auto stageB = [&](int s1, int buf) {    // 2 glds16
#pragma unroll
    for (int c = 0; c < 2; ++c) {
      const short* src = bimg + (((size_t)nt * NSTEPS + s1) * BCH2 + c * 1024 + t) * 8;
      glds16(src, &B_lds[buf][c * 8192 + wid * 512]);
    }
  };
  auto writeA_phi = [&](int buf) {        // x from X_lds (own chunk), params in SGPRs
    const float xa = X_lds[buf][wid * 128 + lane];
    const float xb = X_lds[buf][wid * 128 + 64 + lane];
    short8 va, vb;
#pragma unroll
    for (int b = 0; b < 8; ++b) {
      const float za = fmaf(xa, rwv[b], -rcv[b]);
      const float zb = fmaf(xb, rwv[b], -rcv[b]);
      va[b] = f2bf(exp2f(C2 * za * za));
      vb[b] = f2bf(exp2f(C2 * zb * zb));
    }
    *(short8*)&A_lds[buf][r1 * 64 + (octu ^ (r1 & 7)) * 8] = va;
    *(short8*)&A_lds[buf][r2 * 64 + (octu ^ (r2 & 7)) * 8] = vb;
  };
  auto writeA_cos = [&](int buf, const float4& a0, const float4& a1,
                        const float4& b0, const float4& b1) {
    short8 va, vb;
    va[0] = f2bf(__cosf(a0.x)); va[1] = f2bf(__cosf(a0.y));
    va[2] = f2bf(__cosf(a0.z)); va[3] = f2bf(__cosf(a0.w));
    va[4] = f2bf(__cosf(a1.x)); va[5] = f2bf(__cosf(a1.y));
    va[6] = f2bf(__cosf(a1.z)); va[7] = f2bf(__cosf(a1.w));
    vb[0] = f2bf(__cosf(b0.x)); vb[1] = f2bf(__cosf(b0.y));
    vb[2] = f2bf(__cosf(b0.z)); vb[3] = f2bf(__cosf(b0.w));
    vb[4] = f2bf(__cosf(b1.x)); vb[5] = f2bf(__cosf(b1.y));
    vb[6] = f2bf(__cosf(b1.z)); vb[7] = f2bf(__cosf(b1.w));
    *(short8*)&A_lds[buf][r1 * 64 + (octu ^ (r1 & 7)) * 8] = va;
    *(short8*)&A_lds[buf][r2 * 64 + (octu ^ (r2 & 7)) * 8] = vb;
  };
  auto mma = [&](int buf) {
#pragma unroll
    for (int kk = 0; kk < 2; ++kk) {
      const int sk = kk * 4 + kb;
      short8 af[4], bf[4];
#pragma unroll
      for (int mi = 0; mi < 4; ++mi) {
        const int r = wm * 64 + mi * 16 + l15;
        af[mi] = *(const short8*)&A_lds[buf][r * 64 + (sk ^ (r & 7)) * 8];
      }
#pragma unroll
      for (int ni = 0; ni < 4; ++ni) {
        const int n = wn * 64 + ni * 16 + l15;
        bf[ni] = *(const short8*)&B_lds[buf][n * 64 + (sk ^ (n & 7)) * 8];
      }
#pragma unroll
      for (int mi = 0; mi < 4; ++mi)
#pragma unroll
        for (int ni = 0; ni < 4; ++ni)
          acc[mi][ni] = MFMA(af[mi], bf[ni], acc[mi][ni]);
    }
  };

  // ---- prologue (s0 is always a phi step: s0 <= 54) ----
  loadP(s0);
  stageX(s0, 0);
  stageB(s0, 0);
  asm volatile("s_waitcnt vmcnt(2)" ::: "memory");   // X(s0) landed, keep B(s0)
  writeA_phi(0);
  asm volatile("s_waitcnt lgkmcnt(0)" ::: "memory"); // A(s0) ds_writes drained

  for (int si = 0; si < KT; ++si) {
    const int b = si & 1;
    const int s = s0 + si;
    const bool hasN = (si + 1 < KT);
    const bool nPhi = (s + 1 < PHI_STEPS);
    float4 ca0, ca1, cb0, cb1;
    if (hasN) {
      if (nPhi) {
        loadP(s + 1);                      // s_loads (lgkm domain)
        stageX(s + 1, b ^ 1);              // 2 glds
        stageB(s + 1, b ^ 1);              // 2 glds
        asm volatile("s_waitcnt vmcnt(4)" ::: "memory");   // B(s) landed
      } else {
        const int f0 = (s + 1 - PHI_STEPS) * 64 + octu * 8;
        const float* xr1 = x + (size_t)(m0 + r1) * IN_F + f0;
        const float* xr2 = x + (size_t)(m0 + r2) * IN_F + f0;
        ca0 = *(const float4*)xr1; ca1 = *(const float4*)(xr1 + 4);
        cb0 = *(const float4*)xr2; cb1 = *(const float4*)(xr2 + 4);
        stageB(s + 1, b ^ 1);
        asm volatile("s_waitcnt vmcnt(2)" ::: "memory");   // conservative: B(s) landed
      }
    } else {
      asm volatile("s_waitcnt vmcnt(0)" ::: "memory");
    }
    __builtin_amdgcn_s_barrier();          // tile s published (A ds_writes drained pre-barrier)
    mma(b);
    if (hasN) {
      asm volatile("s_waitcnt vmcnt(2)" ::: "memory");     // X(s+1) landed, keep B(s+1)
      if (nPhi) writeA_phi(b ^ 1);
      else      writeA_cos(b ^ 1, ca0, ca1, cb0, cb1);
      asm volatile("s_waitcnt lgkmcnt(0)" ::: "memory");   // drain A(s+1) ds_writes
    }
    __builtin_amdgcn_s_barrier();          // retire mma reads of buf b
  }

  // ---- epilogue: ks=0 -> out+bias; ks 1..3 -> bf16 partial plane ks-1 ----
#pragma unroll
  for (int ni = 0; ni < 4; ++ni) {
    const int col = n0 + wn * 64 + ni * 16 + l15;
    const float bb = (ks == 0) ? bias[col] : 0.f;
#pragma unroll
    for (int mi = 0; mi < 4; ++mi) {
      const int rb = m0 + wm * 64 + mi * 16 + kb * 4;
#pragma unroll
      for (int r4 = 0; r4 < 4; ++r4) {
        const size_t idx = (size_t)(rb + r4) * OUT_F + col;
        if (ks == 0) out[idx] = acc[mi][ni][r4] + bb;
        else         part[(size_t)(ks - 1) * PART_ELEMS + idx] = f2bf(acc[mi][ni][r4]);
      }
    }
  }
}

extern "C" void kernel_launch(void* const* d_in, const int* in_sizes, int n_in,
                              void* d_out, int out_size, void* d_ws, size_t ws_size,
                              hipStream_t stream) {
  const float* x    = (const float*)d_in[0];
  const float* rw   = (const float*)d_in[1];
  const float* rc   = (const float*)d_in[2];
  const float* w    = (const float*)d_in[3];
  const float* bias = (const float*)d_in[4];
  const float* sb   = (const float*)d_in[5];
  float* out = (float*)d_out;

  const int nrows = in_sizes[0] / IN_F;  // 8192

  const size_t b_bytes    = (size_t)NT2 * NSTEPS * BCH2 * 16;        // 4.72 MB
  const size_t x_bytes    = (size_t)PHI_STEPS * 65536 * 4;           // 16.78 MB
  const size_t p_bytes    = (size_t)3 * PART_ELEMS * sizeof(short);  // 25.2 MB

  // primary: fused-phi GEMM (needs 46.7 MB ws)
  short* bimg = (short*)d_ws;
  float* ximg = (float*)((char*)d_ws + b_bytes);
  short* part = (short*)((char*)d_ws + b_bytes + x_bytes);
  (void)ws_size;  // ws >= 97 MB observed in all runs; 46.7 MB required

  prep_b2<<<NT2 * NSTEPS * BCH2 / 256, 256, 0, stream>>>(w, sb, bimg);
  prep_x<<<dim3(32, 32), 256, 0, stream>>>(x, ximg);
  kan_fx<<<dim3(nrows / 256, 2, 4), 1024, 0, stream>>>(x, ximg, rw, rc,
                                                       bimg, bias, out, part);
  reduce3b<<<2048, 256, 0, stream>>>(part, out);
}